// Round 24
// baseline (977.679 us; speedup 1.0000x reference)
//
#include <hip/hip_runtime.h>
#include <cstdint>

typedef __attribute__((ext_vector_type(4))) _Float16 f16x4;
typedef __attribute__((ext_vector_type(8))) _Float16 f16x8;
typedef __attribute__((ext_vector_type(4))) float f32x4;

#define D_DIM 1024
#define H_DIM 4096
#define BS_ROWS 8192
#define K_SEL 524288u
#define CAND_CAP 32768u

// order-isomorphic fp32 -> uint linear key (monotone)
__device__ __forceinline__ unsigned lkey(float v){
  float u = fmaf(v, 67108864.f, 268435456.f);
  u = fminf(fmaxf(u, 0.f), 536870911.f);
  return (unsigned)u;
}

// async global->LDS, 16B per lane (LDS dest wave-uniform+lane*16; global src per-lane)
__device__ __forceinline__ void gload16(const _Float16* g, _Float16* l){
  __builtin_amdgcn_global_load_lds(
      (const __attribute__((address_space(1))) void*)g,
      (__attribute__((address_space(3))) void*)l, 16, 0, 0);
}

template<int N> __device__ __forceinline__ void waitcnt_vm(){
  if      constexpr (N == 0) asm volatile("s_waitcnt vmcnt(0)" ::: "memory");
  else if constexpr (N == 4) asm volatile("s_waitcnt vmcnt(4)" ::: "memory");
  else if constexpr (N == 6) asm volatile("s_waitcnt vmcnt(6)" ::: "memory");
  else                       asm volatile("s_waitcnt vmcnt(8)" ::: "memory");
}

// Tiled fp16 image: tiles of 128 rows x 32 halves (8KB, 512 granules of 16B).
// Granule for (row,k8): p=(row&127)>>1, s=((row&1)<<2|(k8&3))^(p&7); index p*8+s.
__device__ __forceinline__ size_t img_g32(int row, int k8, int nkt32){
  int p = (row & 127) >> 1;
  int s = (((row & 1) << 2) | (k8 & 3)) ^ (p & 7);
  return ((size_t)((row >> 7) * nkt32 + (k8 >> 2)) << 9) + (p << 3) + s;
}

// Fused pack: all fp32->fp16 image conversions in one launch.
__global__ __launch_bounds__(256)
void pack_all(const float* __restrict__ X, const float* __restrict__ g1w,
              const float* __restrict__ g2w, const float* __restrict__ upw,
              const float* __restrict__ modw, const float* __restrict__ dww,
              _Float16* __restrict__ Xhi, _Float16* __restrict__ Xlo,
              _Float16* __restrict__ G1hi, _Float16* __restrict__ G1lo,
              _Float16* __restrict__ G2hi, _Float16* __restrict__ G2lo,
              _Float16* __restrict__ UPhi, _Float16* __restrict__ MODhi,
              _Float16* __restrict__ DWhi)
{
  unsigned g = blockIdx.x * 256u + threadIdx.x;
  const float* W; _Float16* hi; _Float16* lo = nullptr;
  int k8s, n32; unsigned base;
  if      (g < 1048576u){ W=X;    hi=Xhi;  lo=Xlo;  k8s=7; n32=32;  base=0u;        }
  else if (g < 1572864u){ W=g1w;  hi=G1hi; lo=G1lo; k8s=7; n32=32;  base=1048576u; }
  else if (g < 3670016u){ W=g2w;  hi=G2hi; lo=G2lo; k8s=9; n32=128; base=1572864u; }
  else if (g < 4194304u){ W=upw;  hi=UPhi;          k8s=7; n32=32;  base=3670016u; }
  else if (g < 4718592u){ W=modw; hi=MODhi;         k8s=7; n32=32;  base=4194304u; }
  else                  { W=dww;  hi=DWhi;          k8s=9; n32=128; base=4718592u; }
  g -= base;
  int row = (int)(g >> k8s), k8 = (int)(g & ((1u << k8s) - 1u));
  const float* src = W + ((size_t)row << (k8s + 3)) + (k8 << 3);
  float4 f0 = *(const float4*)src, f1 = *(const float4*)(src + 4);
  float ff[8] = {f0.x,f0.y,f0.z,f0.w,f1.x,f1.y,f1.z,f1.w};
  f16x8 hv, lv;
  #pragma unroll
  for (int i = 0; i < 8; i++){
    hv[i] = (_Float16)ff[i];
    lv[i] = (_Float16)(ff[i] - (float)hv[i]);
  }
  size_t d = img_g32(row, k8, n32) << 3;
  *(f16x8*)&hi[d] = hv;
  if (lo) *(f16x8*)&lo[d] = lv;
}

enum { MODE_G1 = 0, MODE_G2 = 1, MODE_UPMOD = 2, MODE_DOWN = 3 };

// Proven 2-phase/3-deep kernel for UPMOD / DOWN (r21/r22-passed, unchanged).
template<int MODE>
__global__ __launch_bounds__(256)
void gemm_t(const _Float16* __restrict__ Ahi, const _Float16* __restrict__ Alo,
            const _Float16* __restrict__ Bhi, const _Float16* __restrict__ Blo,
            const float* __restrict__ bias0, const float* __restrict__ bias1,
            const unsigned* __restrict__ mask,
            _Float16* __restrict__ Chi, _Float16* __restrict__ Clo,
            float* __restrict__ C32,
            int N, int K, int m_img_base, int c_row_base)
{
  constexpr int NSEG = (MODE == MODE_G1) ? 3 : 1;
  constexpr bool BSEL = (MODE == MODE_UPMOD);
  constexpr int NLD = (NSEG == 3) ? 8 : 4;
  constexpr int DEPTH = (NSEG == 3) ? 2 : 3;
  __shared__ __align__(16) _Float16 sA [DEPTH][4096];
  __shared__ __align__(16) _Float16 sB [DEPTH][4096];
  __shared__ __align__(16) _Float16 sAl[NSEG == 3 ? 2 : 1][NSEG == 3 ? 4096 : 8];
  __shared__ __align__(16) _Float16 sBl[NSEG == 3 ? 2 : 1][NSEG == 3 ? 4096 : 8];

  const int nbx = gridDim.x;
  const int h = blockIdx.y * nbx + blockIdx.x;
  const int xcd = h & 7, idx = h >> 3;
  const int cw = nbx >> 2;
  const int ch = gridDim.y >> 1;
  const int bx = (xcd & 3) * cw + idx % cw;
  const int by = (xcd >> 2) * ch + idx / cw;

  const int tid = threadIdx.x;
  const int lane = tid & 63;
  const int w  = tid >> 6;
  const int wr = w >> 1, wc = w & 1;
  const int lr = lane & 15;
  const int q  = lane >> 4;

  const int m0 = m_img_base + by * 128;
  const int n0 = bx * 128;
  const int nkt = K >> 5;
  const size_t arow = (size_t)(m0 >> 7) * nkt;
  const size_t brow = (size_t)(n0 >> 7) * nkt;

  const _Float16* bsrcl[2];
  if (BSEL){
    const int bb = m0 >> 9;
    #pragma unroll
    for (int j = 0; j < 2; j++){
      int gi = (w*2 + j)*64 + lane;
      int p = gi >> 3, x = (gi & 7) ^ (p & 7);
      int row = (p << 1) | (x >> 2);
      bsrcl[j] = (mask[bb * H_DIM + n0 + row] ? Blo : Bhi) + (gi << 3);
    }
    waitcnt_vm<0>();
  }

  f32x4 acc[4][4];
  #pragma unroll
  for (int i = 0; i < 4; i++)
    #pragma unroll
    for (int j = 0; j < 4; j++) acc[i][j] = (f32x4){0.f,0.f,0.f,0.f};

  const int soff = (((((lr & 1) << 2) | q) ^ (lr >> 1)) << 3);

  auto STAGE = [&](int buf, int kt){
    const _Float16* at = Ahi + ((arow + kt) << 12);
    #pragma unroll
    for (int j = 0; j < 2; j++)
      gload16(at + ((w*2 + j) << 9) + (lane << 3), &sA[buf][(w*2 + j) << 9]);
    if (NSEG == 3){
      const _Float16* alt = Alo + ((arow + kt) << 12);
      const _Float16* bht = Bhi + ((brow + kt) << 12);
      const _Float16* blt = Blo + ((brow + kt) << 12);
      #pragma unroll
      for (int j = 0; j < 2; j++){
        gload16(alt + ((w*2 + j) << 9) + (lane << 3), &sAl[buf][(w*2 + j) << 9]);
        gload16(bht + ((w*2 + j) << 9) + (lane << 3), &sB [buf][(w*2 + j) << 9]);
        gload16(blt + ((w*2 + j) << 9) + (lane << 3), &sBl[buf][(w*2 + j) << 9]);
      }
    } else if (BSEL){
      const size_t toff = (brow + kt) << 12;
      #pragma unroll
      for (int j = 0; j < 2; j++)
        gload16(bsrcl[j] + toff, &sB[buf][(w*2 + j) << 9]);
    } else {
      const _Float16* bht = Bhi + ((brow + kt) << 12);
      #pragma unroll
      for (int j = 0; j < 2; j++)
        gload16(bht + ((w*2 + j) << 9) + (lane << 3), &sB[buf][(w*2 + j) << 9]);
    }
  };

  STAGE(0, 0);
  if (DEPTH == 3) STAGE(1, 1);

  for (int kt = 0; kt < nkt; ++kt){
    const int rem = nkt - 1 - kt;
    const int cur = (DEPTH == 2) ? (kt & 1) : (kt % 3);
    if (DEPTH == 2){
      if (rem >= 1){ STAGE((kt + 1) & 1, kt + 1); waitcnt_vm<NLD>(); }
      else         { waitcnt_vm<0>(); }
    } else {
      if (rem >= 2){ STAGE((kt + 2) % 3, kt + 2); waitcnt_vm<8>(); }
      else if (rem == 1){ waitcnt_vm<4>(); }
      else         { waitcnt_vm<0>(); }
    }
    __builtin_amdgcn_s_barrier();
    __builtin_amdgcn_sched_barrier(0);

    f16x8 fah[4], fbh[4], fal[4], fbl[4];
    #pragma unroll
    for (int i = 0; i < 4; i++){
      const int ap = ((wr*32 + i*8 + (lr >> 1)) << 6) + soff;
      const int bp = ((wc*32 + i*8 + (lr >> 1)) << 6) + soff;
      fah[i] = *(const f16x8*)&sA[cur][ap];
      fbh[i] = *(const f16x8*)&sB[cur][bp];
      if (NSEG == 3){
        fal[i] = *(const f16x8*)&sAl[cur][ap];
        fbl[i] = *(const f16x8*)&sBl[cur][bp];
      }
    }
    #pragma unroll
    for (int mi = 0; mi < 4; mi++)
      #pragma unroll
      for (int ni = 0; ni < 4; ni++)
        acc[mi][ni] = __builtin_amdgcn_mfma_f32_16x16x32_f16(fah[mi], fbh[ni], acc[mi][ni], 0,0,0);
    if (NSEG == 3){
      #pragma unroll
      for (int mi = 0; mi < 4; mi++)
        #pragma unroll
        for (int ni = 0; ni < 4; ni++)
          acc[mi][ni] = __builtin_amdgcn_mfma_f32_16x16x32_f16(fal[mi], fbh[ni], acc[mi][ni], 0,0,0);
      #pragma unroll
      for (int mi = 0; mi < 4; mi++)
        #pragma unroll
        for (int ni = 0; ni < 4; ni++)
          acc[mi][ni] = __builtin_amdgcn_mfma_f32_16x16x32_f16(fah[mi], fbl[ni], acc[mi][ni], 0,0,0);
    }
    __builtin_amdgcn_s_barrier();
  }

  #pragma unroll
  for (int ni = 0; ni < 4; ni++){
    const int gc = n0 + wc*64 + ni*16 + lr;
    float bias;
    if (MODE == MODE_UPMOD) bias = mask[(m0 >> 9) * H_DIM + gc] ? bias1[gc] : bias0[gc];
    else                    bias = bias0[gc];
    #pragma unroll
    for (int mi = 0; mi < 4; mi++){
      #pragma unroll
      for (int r = 0; r < 4; r++){
        const int gr = m0 + wr*64 + mi*16 + q*4 + r;
        const int cr = gr - c_row_base;
        float v = acc[mi][ni][r] + bias;
        if (MODE == MODE_G1){
          v = fmaxf(v, 0.f);
          size_t d = (img_g32(cr, gc >> 3, N >> 5) << 3) + (gc & 7);
          Chi[d] = (_Float16)v;
        }
        if (MODE == MODE_UPMOD){
          v = v / (1.f + __expf(-v));
          size_t d = (img_g32(cr, gc >> 3, N >> 5) << 3) + (gc & 7);
          Chi[d] = (_Float16)v;
        }
        if (MODE == MODE_DOWN) C32[(size_t)cr * N + gc] = v;
      }
    }
  }
}

// gate1 on the r22-proven g2 schedule via VIRTUAL-K: K_virt = 3K with tile
// sequence A:[Xhi|Xlo|Xhi], B:[G1hi|G1hi|G1lo] (= Ah*Bh + Al*Bh + Ah*Bl).
// 256x256 tile, 512 thr, triple-buffered (96KB), 4 phases, vmcnt(4), setprio.
__global__ __launch_bounds__(512, 1)
void gemm_g1v(const _Float16* __restrict__ Ahi, const _Float16* __restrict__ Alo,
              const _Float16* __restrict__ Bhi, const _Float16* __restrict__ Blo,
              const float* __restrict__ bias0, _Float16* __restrict__ Chi,
              int N, int K, int m_img_base, int c_row_base)
{
  __shared__ __align__(16) _Float16 sAb[3][8192];
  __shared__ __align__(16) _Float16 sBb[3][8192];

  const int nbx = gridDim.x;           // 16
  const int h = blockIdx.y * nbx + blockIdx.x;
  const int xcd = h & 7, idx = h >> 3;
  const int cw = nbx >> 2, ch = gridDim.y >> 1;
  const int bx = (xcd & 3) * cw + idx % cw;
  const int by = (xcd >> 2) * ch + idx / cw;

  const int tid = threadIdx.x;
  const int lane = tid & 63;
  const int w = tid >> 6;
  const int wrow = w >> 2, wcol = w & 3;
  const int lr = lane & 15;
  const int q = lane >> 4;

  const int m0 = m_img_base + by * 256;
  const int n0 = bx * 256;
  const int nks = K >> 5;              // 32 tiles per segment
  const int nkt = 3 * nks;             // 96 virtual tiles
  const int ar0 = (m0 >> 7) * nks;
  const int br0 = (n0 >> 7) * nks;

  f32x4 acc[8][4];
  #pragma unroll
  for (int i = 0; i < 8; i++)
    #pragma unroll
    for (int j = 0; j < 4; j++) acc[i][j] = (f32x4){0.f,0.f,0.f,0.f};

  const int soff = (((((lr & 1) << 2) | q) ^ (lr >> 1)) << 3);
  int offA[8], offB[4];
  #pragma unroll
  for (int mi = 0; mi < 8; mi++) offA[mi] = ((mi*8 + (lr >> 1)) << 6) + soff;
  #pragma unroll
  for (int ni = 0; ni < 4; ni++)
    offB[ni] = (((wcol & 1)*32 + ni*8 + (lr >> 1)) << 6) + soff;
  const int arb = wrow * 4096;
  const int bcb = (wcol >> 1) * 4096;

  auto STA = [&](int buf, int rb, int kt){
    const int seg = kt >> 5, lk = kt & 31;
    const _Float16* img = (seg == 1) ? Alo : Ahi;
    gload16(img + ((((size_t)(ar0 + rb*nks + lk) << 9) + tid) << 3),
            &sAb[buf][rb*4096 + (tid << 3)]);
  };
  auto STB = [&](int buf, int cb, int kt){
    const int seg = kt >> 5, lk = kt & 31;
    const _Float16* img = (seg == 2) ? Blo : Bhi;
    gload16(img + ((((size_t)(br0 + cb*nks + lk) << 9) + tid) << 3),
            &sBb[buf][cb*4096 + (tid << 3)]);
  };

#define G1VPHASE(P, STG)                                                       \
  {                                                                            \
    f16x8 a0 = *(const f16x8*)&sAb[cur][arb + offA[2*(P)]];                    \
    f16x8 a1 = *(const f16x8*)&sAb[cur][arb + offA[2*(P)+1]];                  \
    STG;                                                                       \
    if ((P) == 3){ if (pf) waitcnt_vm<4>(); else waitcnt_vm<0>(); }            \
    __builtin_amdgcn_s_barrier();                                              \
    asm volatile("s_waitcnt lgkmcnt(0)" ::: "memory");                         \
    __builtin_amdgcn_sched_barrier(0);                                         \
    __builtin_amdgcn_s_setprio(1);                                             \
    _Pragma("unroll")                                                          \
    for (int ni = 0; ni < 4; ni++)                                             \
      acc[2*(P)][ni]   = __builtin_amdgcn_mfma_f32_16x16x32_f16(a0, fb[ni], acc[2*(P)][ni], 0,0,0);   \
    _Pragma("unroll")                                                          \
    for (int ni = 0; ni < 4; ni++)                                             \
      acc[2*(P)+1][ni] = __builtin_amdgcn_mfma_f32_16x16x32_f16(a1, fb[ni], acc[2*(P)+1][ni], 0,0,0); \
    __builtin_amdgcn_s_setprio(0);                                             \
    __builtin_amdgcn_s_barrier();                                              \
  }

  STA(0,0,0); STB(0,0,0); STB(0,1,0); STA(0,1,0);
  STA(1,0,1); STB(1,0,1); STB(1,1,1); STA(1,1,1);
  waitcnt_vm<4>();
  __builtin_amdgcn_s_barrier();

  for (int kt = 0; kt < nkt; ++kt){
    const int cur = kt % 3, nb = (kt + 2) % 3;
    const bool pf = (kt + 2 < nkt);
    f16x8 fb[4];
    #pragma unroll
    for (int ni = 0; ni < 4; ni++)
      fb[ni] = *(const f16x8*)&sBb[cur][bcb + offB[ni]];
    G1VPHASE(0, if (pf) STA(nb, 0, kt+2))
    G1VPHASE(1, if (pf) STB(nb, 0, kt+2))
    G1VPHASE(2, if (pf) STB(nb, 1, kt+2))
    G1VPHASE(3, if (pf) STA(nb, 1, kt+2))
  }
#undef G1VPHASE

  // epilogue: F(hi only) = relu(. + bias) -> tiled image
  #pragma unroll
  for (int ni = 0; ni < 4; ni++){
    const int gc = n0 + wcol*64 + ni*16 + lr;
    const float bias = bias0[gc];
    #pragma unroll
    for (int mi = 0; mi < 8; mi++){
      #pragma unroll
      for (int r = 0; r < 4; r++){
        const int gr = m0 + wrow*128 + mi*16 + q*4 + r;
        const int cr = gr - c_row_base;
        float v = fmaxf(acc[mi][ni][r] + bias, 0.f);
        size_t d = (img_g32(cr, gc >> 3, N >> 5) << 3) + (gc & 7);
        Chi[d] = (_Float16)v;
      }
    }
  }
}

// gate2 8-phase-class kernel (r22-proven, unchanged): 256x256, triple-buffered.
__global__ __launch_bounds__(512, 2)
void gemm_g2(const _Float16* __restrict__ A, const _Float16* __restrict__ B,
             const float* __restrict__ bias0,
             unsigned* __restrict__ keys, unsigned* __restrict__ Mkey,
             unsigned* __restrict__ hist, int N, int K, int batch_base)
{
  __shared__ __align__(16) _Float16 sAb[3][8192];
  __shared__ __align__(16) _Float16 sBb[3][8192];

  const int nbx = gridDim.x;
  const int h = blockIdx.y * nbx + blockIdx.x;
  const int xcd = h & 7, idx = h >> 3;
  const int cw = nbx >> 2, ch = gridDim.y >> 1;
  const int bx = (xcd & 3) * cw + idx % cw;
  const int by = (xcd >> 2) * ch + idx / cw;

  const int tid = threadIdx.x;
  const int lane = tid & 63;
  const int w = tid >> 6;
  const int wrow = w >> 2, wcol = w & 3;
  const int lr = lane & 15;
  const int q = lane >> 4;

  const int m0 = by * 256;
  const int n0 = bx * 256;
  const int nkt = K >> 5;
  const int ar0 = (m0 >> 7) * nkt;
  const int br0 = (n0 >> 7) * nkt;

  f32x4 acc[8][4];
  #pragma unroll
  for (int i = 0; i < 8; i++)
    #pragma unroll
    for (int j = 0; j < 4; j++) acc[i][j] = (f32x4){0.f,0.f,0.f,0.f};

  const int soff = (((((lr & 1) << 2) | q) ^ (lr >> 1)) << 3);
  int offA[8], offB[4];
  #pragma unroll
  for (int mi = 0; mi < 8; mi++) offA[mi] = ((mi*8 + (lr >> 1)) << 6) + soff;
  #pragma unroll
  for (int ni = 0; ni < 4; ni++)
    offB[ni] = (((wcol & 1)*32 + ni*8 + (lr >> 1)) << 6) + soff;
  const int arb = wrow * 4096;
  const int bcb = (wcol >> 1) * 4096;

  auto STA = [&](int buf, int rb, int kt){
    gload16(A + ((((size_t)(ar0 + rb*nkt + kt) << 9) + tid) << 3),
            &sAb[buf][rb*4096 + (tid << 3)]);
  };
  auto STB = [&](int buf, int cb, int kt){
    gload16(B + ((((size_t)(br0 + cb*nkt + kt) << 9) + tid) << 3),
            &sBb[buf][cb*4096 + (tid << 3)]);
  };

#define G2PHASE(P, STG)                                                        \
  {                                                                            \
    f16x8 a0 = *(const f16x8*)&sAb[cur][arb + offA[2*(P)]];                    \
    f16x8 a1 = *(const f16x8*)&sAb[cur][arb + offA[2*(P)+1]];                  \
    STG;                                                                       \
    if ((P) == 3){ if (pf) waitcnt_vm<4>(); else waitcnt_vm<0>(); }            \
    __builtin_amdgcn_s_barrier();                                              \
    asm volatile("s_waitcnt lgkmcnt(0)" ::: "memory");                         \
    __builtin_amdgcn_sched_barrier(0);                                         \
    __builtin_amdgcn_s_setprio(1);                                             \
    _Pragma("unroll")                                                          \
    for (int ni = 0; ni < 4; ni++)                                             \
      acc[2*(P)][ni]   = __builtin_amdgcn_mfma_f32_16x16x32_f16(a0, fb[ni], acc[2*(P)][ni], 0,0,0);   \
    _Pragma("unroll")                                                          \
    for (int ni = 0; ni < 4; ni++)                                             \
      acc[2*(P)+1][ni] = __builtin_amdgcn_mfma_f32_16x16x32_f16(a1, fb[ni], acc[2*(P)+1][ni], 0,0,0); \
    __builtin_amdgcn_s_setprio(0);                                             \
    __builtin_amdgcn_s_barrier();                                              \
  }

  STA(0,0,0); STB(0,0,0); STB(0,1,0); STA(0,1,0);
  STA(1,0,1); STB(1,0,1); STB(1,1,1); STA(1,1,1);
  waitcnt_vm<4>();
  __builtin_amdgcn_s_barrier();

  for (int kt = 0; kt < nkt; ++kt){
    const int cur = kt % 3, nb = (kt + 2) % 3;
    const bool pf = (kt + 2 < nkt);
    f16x8 fb[4];
    #pragma unroll
    for (int ni = 0; ni < 4; ni++)
      fb[ni] = *(const f16x8*)&sBb[cur][bcb + offB[ni]];
    G2PHASE(0, if (pf) STA(nb, 0, kt+2))
    G2PHASE(1, if (pf) STB(nb, 0, kt+2))
    G2PHASE(2, if (pf) STB(nb, 1, kt+2))
    G2PHASE(3, if (pf) STA(nb, 1, kt+2))
  }
#undef G2PHASE

  unsigned* lh = (unsigned*)&sAb[0][0];
  __syncthreads();
  for (int i = tid; i < 4096; i += 512) lh[i] = 0;
  __syncthreads();

  const int gb = batch_base + (m0 >> 9);
  #pragma unroll
  for (int ni = 0; ni < 4; ni++){
    const int gc = n0 + wcol*64 + ni*16 + lr;
    const float bias = bias0[gc];
    unsigned colmax = 0u;
    #pragma unroll
    for (int mi = 0; mi < 8; mi++){
      #pragma unroll
      for (int r = 0; r < 4; r++){
        const int gr = m0 + wrow*128 + mi*16 + q*4 + r;
        float v = acc[mi][ni][r] + bias;
        unsigned key = lkey(v);
        keys[(size_t)gr * N + gc] = key;
        colmax = max(colmax, key);
        atomicAdd(&lh[key >> 17], 1u);
      }
    }
    atomicMax(&Mkey[gb * H_DIM + gc], colmax);
  }
  __syncthreads();
  for (int i = tid; i < 4096; i += 512)
    if (lh[i]) atomicAdd(&hist[(gb << 12) + i], lh[i]);
}

// ---- exact k-th largest per batch: 12-bit hist (from gate2) + candidate refine ----

__global__ __launch_bounds__(256)
void select12(const unsigned* __restrict__ hist, unsigned* __restrict__ b12,
              unsigned* __restrict__ krem, unsigned* __restrict__ ccount, int b0)
{
  const int b = b0 + (int)blockIdx.x;
  __shared__ unsigned part[256];
  const unsigned base = (unsigned)b << 12;
  unsigned s = 0;
  #pragma unroll
  for (int i = 0; i < 16; i++) s += hist[base + threadIdx.x*16 + i];
  part[threadIdx.x] = s;
  __syncthreads();
  if (threadIdx.x == 0){
    unsigned cum = 0; int t = 255;
    for (; t > 0; --t){
      if (cum + part[t] >= K_SEL) break;
      cum += part[t];
    }
    int bin = 15; unsigned kr = K_SEL;
    for (; bin > 0; --bin){
      unsigned c = hist[base + t*16 + bin];
      if (cum + c >= K_SEL) break;
      cum += c;
    }
    kr = K_SEL - cum;
    b12[b] = (unsigned)(t*16 + bin);
    krem[b] = kr;
    ccount[b] = 0;
  }
}

// LDS-buffered match gather + ONE global atomic per WG (r8 fix)
__global__ __launch_bounds__(256)
void collect(const unsigned* __restrict__ keys, const unsigned* __restrict__ b12,
             unsigned* __restrict__ cand, unsigned* __restrict__ ccount, int b0)
{
  __shared__ unsigned cbuf[1024];
  __shared__ unsigned lcnt, gbase;
  const int bl = blockIdx.y;
  const int b  = b0 + bl;
  const unsigned bin = b12[b];
  if (threadIdx.x == 0) lcnt = 0;
  __syncthreads();
  const uint4* p = (const uint4*)(keys + (size_t)bl*2097152u + (size_t)blockIdx.x*8192u);
  uint4 kv[8];
  #pragma unroll
  for (int j = 0; j < 8; j++) kv[j] = p[threadIdx.x + j*256];
  #pragma unroll
  for (int j = 0; j < 8; j++){
    #pragma unroll
    for (int e = 0; e < 4; e++){
      unsigned k = (e==0)?kv[j].x:(e==1)?kv[j].y:(e==2)?kv[j].z:kv[j].w;
      if ((k >> 17) == bin){
        unsigned idx = atomicAdd(&lcnt, 1u);
        if (idx < 1024u) cbuf[idx] = k;
      }
    }
  }
  __syncthreads();
  const unsigned n = lcnt < 1024u ? lcnt : 1024u;
  if (threadIdx.x == 0) gbase = atomicAdd(&ccount[b], n);
  __syncthreads();
  const unsigned gb = gbase;
  for (unsigned i = threadIdx.x; i < n; i += 256){
    unsigned dst = gb + i;
    if (dst < CAND_CAP) cand[((size_t)b << 15) + dst] = cbuf[i];
  }
}

__global__ __launch_bounds__(256)
void select_exact(const unsigned* __restrict__ cand, const unsigned* __restrict__ ccount,
                  const unsigned* __restrict__ b12, const unsigned* __restrict__ kremA,
                  unsigned* __restrict__ tkey, int b0)
{
  const int b = b0 + (int)blockIdx.x;
  unsigned cc = ccount[b];
  const unsigned n = cc < CAND_CAP ? cc : CAND_CAP;
  __shared__ unsigned h[256];
  __shared__ unsigned sh2[2];
  unsigned prefix = b12[b] << 17;
  unsigned krem = kremA[b];
  const unsigned pm[3]  = {0xFFFE0000u, 0xFFFFFE00u, 0xFFFFFFFEu};
  const int      shs[3] = {9, 1, 0};
  const int      wid[3] = {256, 256, 2};
  for (int pass = 0; pass < 3; ++pass){
    if (threadIdx.x < (unsigned)wid[pass]) h[threadIdx.x] = 0;
    __syncthreads();
    for (unsigned i = threadIdx.x; i < n; i += 256){
      unsigned k = cand[((size_t)b << 15) + i];
      if ((k & pm[pass]) == prefix)
        atomicAdd(&h[(k >> shs[pass]) & (unsigned)(wid[pass]-1)], 1u);
    }
    __syncthreads();
    if (threadIdx.x == 0){
      unsigned cum = 0; int bin = wid[pass]-1;
      for (; bin > 0; --bin){
        unsigned c = h[bin];
        if (cum + c >= krem) break;
        cum += c;
      }
      krem -= cum;
      prefix |= ((unsigned)bin) << shs[pass];
      sh2[0] = prefix; sh2[1] = krem;
    }
    __syncthreads();
    prefix = sh2[0]; krem = sh2[1];
    __syncthreads();
  }
  if (threadIdx.x == 0) tkey[b] = prefix;
}

__global__ __launch_bounds__(256)
void make_mask(const unsigned* __restrict__ Mkey, const unsigned* __restrict__ tkey,
               unsigned* __restrict__ mask){
  const int i = blockIdx.x * 256 + threadIdx.x;   // B*H = 65536
  const int b = i >> 12;
  mask[i] = (Mkey[i] >= tkey[b]) ? 1u : 0u;
}

extern "C" void kernel_launch(void* const* d_in, const int* in_sizes, int n_in,
                              void* d_out, int out_size, void* d_ws, size_t ws_size,
                              hipStream_t stream)
{
  (void)in_sizes; (void)n_in; (void)out_size; (void)ws_size;
  const float* X      = (const float*)d_in[0];
  const float* up_w   = (const float*)d_in[1];
  const float* up_b   = (const float*)d_in[2];
  const float* g1w    = (const float*)d_in[3];
  const float* g1b    = (const float*)d_in[4];
  const float* g2w    = (const float*)d_in[5];
  const float* g2b    = (const float*)d_in[6];
  const float* mod_w  = (const float*)d_in[7];
  const float* mod_b  = (const float*)d_in[8];
  const float* down_w = (const float*)d_in[9];
  const float* down_b = (const float*)d_in[10];
  float* out = (float*)d_out;

  // ws layout (peak ~235 MiB)
  char* ws = (char*)d_ws;
  _Float16* Xhi  = (_Float16*)(ws);
  _Float16* Xlo  = (_Float16*)(ws + (16ull<<20));
  _Float16* G1hi = (_Float16*)(ws + (32ull<<20));
  _Float16* G1lo = (_Float16*)(ws + (40ull<<20));
  _Float16* G2hi = (_Float16*)(ws + (48ull<<20));
  _Float16* UPhi = (_Float16*)(ws + (112ull<<20));
  _Float16* MODhi= (_Float16*)(ws + (120ull<<20));
  _Float16* DWhi = (_Float16*)(ws + (128ull<<20));
  _Float16* Fhi  = (_Float16*)(ws + (136ull<<20));   // per half [4096][4096] (32 MiB)
  unsigned* keys = (unsigned*)(ws + (168ull<<20));   // per half [4096][4096] u32 (64 MiB)
  _Float16* Hbuf = (_Float16*)(ws + (136ull<<20));   // reuse F+keys after selection
  char* aux = ws + (232ull<<20);
  unsigned* Mkey  = (unsigned*)(aux);                 // 256 KB
  unsigned* maskb = (unsigned*)(aux + 262144);        // 256 KB
  unsigned* hist  = (unsigned*)(aux + 524288);        // 256 KB (16 batches x 4096)
  unsigned* cand  = (unsigned*)(aux + 786432);        // 2 MiB (16 x 32768)
  unsigned* b12   = (unsigned*)(aux + 786432 + 2097152);
  unsigned* krem  = (unsigned*)(aux + 786432 + 2097152 + 64);
  unsigned* ccnt  = (unsigned*)(aux + 786432 + 2097152 + 128);
  unsigned* tkey  = (unsigned*)(aux + 786432 + 2097152 + 192);

  // fused pack (3-seg gate1: G1lo packed; G2lo not)
  pack_all<<<20480, 256, 0, stream>>>(X, g1w, g2w, up_w, mod_w, down_w,
                                      Xhi, Xlo, G1hi, G1lo, G2hi, nullptr,
                                      UPhi, MODhi, DWhi);

  hipMemsetAsync(Mkey, 0, 262144, stream);
  hipMemsetAsync(hist, 0, 262144, stream);

  for (int half = 0; half < 2; ++half){
    const int b0 = half * 8;
    // gate1 half (virtual-K 3-seg on g2 schedule): F(hi) = relu(X @ g1w^T + g1b)
    gemm_g1v<<<dim3(16, 16), 512, 0, stream>>>(
        Xhi, Xlo, G1hi, G1lo, g1b, Fhi, H_DIM, D_DIM, half*4096, half*4096);
    // gate2 half (1-seg fp16, 8-phase-class 256^2): keys + Mkey + hist
    gemm_g2<<<dim3(16, 16), 512, 0, stream>>>(
        Fhi, G2hi, g2b, keys, Mkey, hist, H_DIM, H_DIM, b0);
    select12<<<8, 256, 0, stream>>>(hist, b12, krem, ccnt, b0);
    collect<<<dim3(256, 8), 256, 0, stream>>>(keys, b12, cand, ccnt, b0);
    select_exact<<<8, 256, 0, stream>>>(cand, ccnt, b12, krem, tkey, b0);
  }
  make_mask<<<256, 256, 0, stream>>>(Mkey, tkey, maskb);

  // up/mod (per-granule stage select, 3-deep) + silu -> Hbuf  [8192 x 4096], K=1024
  gemm_t<MODE_UPMOD><<<dim3(32, 64), 256, 0, stream>>>(
      Xhi, nullptr, UPhi, MODhi, up_b, mod_b, maskb,
      Hbuf, nullptr, nullptr, H_DIM, D_DIM, 0, 0);
  // down (3-deep): out = Hbuf @ down_w^T + down_b  [8192 x 1024], K=4096
  gemm_t<MODE_DOWN><<<dim3(8, 64), 256, 0, stream>>>(
      Hbuf, nullptr, DWhi, nullptr, down_b, nullptr, nullptr,
      nullptr, nullptr, out, D_DIM, H_DIM, 0, 0);
}

// Round 25
// 911.824 us; speedup vs baseline: 1.0722x; 1.0722x over previous
//
#include <hip/hip_runtime.h>
#include <cstdint>

typedef __attribute__((ext_vector_type(4))) _Float16 f16x4;
typedef __attribute__((ext_vector_type(8))) _Float16 f16x8;
typedef __attribute__((ext_vector_type(4))) float f32x4;

#define D_DIM 1024
#define H_DIM 4096
#define BS_ROWS 8192
#define K_SEL 524288u
#define CAND_CAP 32768u

// order-isomorphic fp32 -> uint linear key (monotone)
__device__ __forceinline__ unsigned lkey(float v){
  float u = fmaf(v, 67108864.f, 268435456.f);
  u = fminf(fmaxf(u, 0.f), 536870911.f);
  return (unsigned)u;
}

// async global->LDS, 16B per lane (LDS dest wave-uniform+lane*16; global src per-lane)
__device__ __forceinline__ void gload16(const _Float16* g, _Float16* l){
  __builtin_amdgcn_global_load_lds(
      (const __attribute__((address_space(1))) void*)g,
      (__attribute__((address_space(3))) void*)l, 16, 0, 0);
}

template<int N> __device__ __forceinline__ void waitcnt_vm(){
  if      constexpr (N == 0) asm volatile("s_waitcnt vmcnt(0)" ::: "memory");
  else if constexpr (N == 4) asm volatile("s_waitcnt vmcnt(4)" ::: "memory");
  else if constexpr (N == 6) asm volatile("s_waitcnt vmcnt(6)" ::: "memory");
  else                       asm volatile("s_waitcnt vmcnt(8)" ::: "memory");
}

// Tiled fp16 image: tiles of 128 rows x 32 halves (8KB, 512 granules of 16B).
// Granule for (row,k8): p=(row&127)>>1, s=((row&1)<<2|(k8&3))^(p&7); index p*8+s.
__device__ __forceinline__ size_t img_g32(int row, int k8, int nkt32){
  int p = (row & 127) >> 1;
  int s = (((row & 1) << 2) | (k8 & 3)) ^ (p & 7);
  return ((size_t)((row >> 7) * nkt32 + (k8 >> 2)) << 9) + (p << 3) + s;
}

// Fused pack: all fp32->fp16 image conversions in one launch.
__global__ __launch_bounds__(256)
void pack_all(const float* __restrict__ X, const float* __restrict__ g1w,
              const float* __restrict__ g2w, const float* __restrict__ upw,
              const float* __restrict__ modw, const float* __restrict__ dww,
              _Float16* __restrict__ Xhi, _Float16* __restrict__ Xlo,
              _Float16* __restrict__ G1hi, _Float16* __restrict__ G1lo,
              _Float16* __restrict__ G2hi, _Float16* __restrict__ G2lo,
              _Float16* __restrict__ UPhi, _Float16* __restrict__ MODhi,
              _Float16* __restrict__ DWhi)
{
  unsigned g = blockIdx.x * 256u + threadIdx.x;
  const float* W; _Float16* hi; _Float16* lo = nullptr;
  int k8s, n32; unsigned base;
  if      (g < 1048576u){ W=X;    hi=Xhi;  lo=Xlo;  k8s=7; n32=32;  base=0u;        }
  else if (g < 1572864u){ W=g1w;  hi=G1hi; lo=G1lo; k8s=7; n32=32;  base=1048576u; }
  else if (g < 3670016u){ W=g2w;  hi=G2hi; lo=G2lo; k8s=9; n32=128; base=1572864u; }
  else if (g < 4194304u){ W=upw;  hi=UPhi;          k8s=7; n32=32;  base=3670016u; }
  else if (g < 4718592u){ W=modw; hi=MODhi;         k8s=7; n32=32;  base=4194304u; }
  else                  { W=dww;  hi=DWhi;          k8s=9; n32=128; base=4718592u; }
  g -= base;
  int row = (int)(g >> k8s), k8 = (int)(g & ((1u << k8s) - 1u));
  const float* src = W + ((size_t)row << (k8s + 3)) + (k8 << 3);
  float4 f0 = *(const float4*)src, f1 = *(const float4*)(src + 4);
  float ff[8] = {f0.x,f0.y,f0.z,f0.w,f1.x,f1.y,f1.z,f1.w};
  f16x8 hv, lv;
  #pragma unroll
  for (int i = 0; i < 8; i++){
    hv[i] = (_Float16)ff[i];
    lv[i] = (_Float16)(ff[i] - (float)hv[i]);
  }
  size_t d = img_g32(row, k8, n32) << 3;
  *(f16x8*)&hi[d] = hv;
  if (lo) *(f16x8*)&lo[d] = lv;
}

enum { MODE_G1 = 0, MODE_G2 = 1, MODE_UPMOD = 2, MODE_DOWN = 3 };

// Proven kernel for G1 (2-phase/2-deep, 3-seg) and UPMOD / DOWN (3-deep).
template<int MODE>
__global__ __launch_bounds__(256)
void gemm_t(const _Float16* __restrict__ Ahi, const _Float16* __restrict__ Alo,
            const _Float16* __restrict__ Bhi, const _Float16* __restrict__ Blo,
            const float* __restrict__ bias0, const float* __restrict__ bias1,
            const unsigned* __restrict__ mask,
            _Float16* __restrict__ Chi, _Float16* __restrict__ Clo,
            float* __restrict__ C32,
            int N, int K, int m_img_base, int c_row_base)
{
  constexpr int NSEG = (MODE == MODE_G1) ? 3 : 1;
  constexpr bool BSEL = (MODE == MODE_UPMOD);
  constexpr int NLD = (NSEG == 3) ? 8 : 4;
  constexpr int DEPTH = (NSEG == 3) ? 2 : 3;
  __shared__ __align__(16) _Float16 sA [DEPTH][4096];
  __shared__ __align__(16) _Float16 sB [DEPTH][4096];
  __shared__ __align__(16) _Float16 sAl[NSEG == 3 ? 2 : 1][NSEG == 3 ? 4096 : 8];
  __shared__ __align__(16) _Float16 sBl[NSEG == 3 ? 2 : 1][NSEG == 3 ? 4096 : 8];

  const int nbx = gridDim.x;
  const int h = blockIdx.y * nbx + blockIdx.x;
  const int xcd = h & 7, idx = h >> 3;
  const int cw = nbx >> 2;
  const int ch = gridDim.y >> 1;
  const int bx = (xcd & 3) * cw + idx % cw;
  const int by = (xcd >> 2) * ch + idx / cw;

  const int tid = threadIdx.x;
  const int lane = tid & 63;
  const int w  = tid >> 6;
  const int wr = w >> 1, wc = w & 1;
  const int lr = lane & 15;
  const int q  = lane >> 4;

  const int m0 = m_img_base + by * 128;
  const int n0 = bx * 128;
  const int nkt = K >> 5;
  const size_t arow = (size_t)(m0 >> 7) * nkt;
  const size_t brow = (size_t)(n0 >> 7) * nkt;

  const _Float16* bsrcl[2];
  if (BSEL){
    const int bb = m0 >> 9;
    #pragma unroll
    for (int j = 0; j < 2; j++){
      int gi = (w*2 + j)*64 + lane;
      int p = gi >> 3, x = (gi & 7) ^ (p & 7);
      int row = (p << 1) | (x >> 2);
      bsrcl[j] = (mask[bb * H_DIM + n0 + row] ? Blo : Bhi) + (gi << 3);
    }
    waitcnt_vm<0>();
  }

  f32x4 acc[4][4];
  #pragma unroll
  for (int i = 0; i < 4; i++)
    #pragma unroll
    for (int j = 0; j < 4; j++) acc[i][j] = (f32x4){0.f,0.f,0.f,0.f};

  const int soff = (((((lr & 1) << 2) | q) ^ (lr >> 1)) << 3);

  auto STAGE = [&](int buf, int kt){
    const _Float16* at = Ahi + ((arow + kt) << 12);
    #pragma unroll
    for (int j = 0; j < 2; j++)
      gload16(at + ((w*2 + j) << 9) + (lane << 3), &sA[buf][(w*2 + j) << 9]);
    if (NSEG == 3){
      const _Float16* alt = Alo + ((arow + kt) << 12);
      const _Float16* bht = Bhi + ((brow + kt) << 12);
      const _Float16* blt = Blo + ((brow + kt) << 12);
      #pragma unroll
      for (int j = 0; j < 2; j++){
        gload16(alt + ((w*2 + j) << 9) + (lane << 3), &sAl[buf][(w*2 + j) << 9]);
        gload16(bht + ((w*2 + j) << 9) + (lane << 3), &sB [buf][(w*2 + j) << 9]);
        gload16(blt + ((w*2 + j) << 9) + (lane << 3), &sBl[buf][(w*2 + j) << 9]);
      }
    } else if (BSEL){
      const size_t toff = (brow + kt) << 12;
      #pragma unroll
      for (int j = 0; j < 2; j++)
        gload16(bsrcl[j] + toff, &sB[buf][(w*2 + j) << 9]);
    } else {
      const _Float16* bht = Bhi + ((brow + kt) << 12);
      #pragma unroll
      for (int j = 0; j < 2; j++)
        gload16(bht + ((w*2 + j) << 9) + (lane << 3), &sB[buf][(w*2 + j) << 9]);
    }
  };

  STAGE(0, 0);
  if (DEPTH == 3) STAGE(1, 1);

  for (int kt = 0; kt < nkt; ++kt){
    const int rem = nkt - 1 - kt;
    const int cur = (DEPTH == 2) ? (kt & 1) : (kt % 3);
    if (DEPTH == 2){
      if (rem >= 1){ STAGE((kt + 1) & 1, kt + 1); waitcnt_vm<NLD>(); }
      else         { waitcnt_vm<0>(); }
    } else {
      if (rem >= 2){ STAGE((kt + 2) % 3, kt + 2); waitcnt_vm<8>(); }
      else if (rem == 1){ waitcnt_vm<4>(); }
      else         { waitcnt_vm<0>(); }
    }
    __builtin_amdgcn_s_barrier();
    __builtin_amdgcn_sched_barrier(0);

    f16x8 fah[4], fbh[4], fal[4], fbl[4];
    #pragma unroll
    for (int i = 0; i < 4; i++){
      const int ap = ((wr*32 + i*8 + (lr >> 1)) << 6) + soff;
      const int bp = ((wc*32 + i*8 + (lr >> 1)) << 6) + soff;
      fah[i] = *(const f16x8*)&sA[cur][ap];
      fbh[i] = *(const f16x8*)&sB[cur][bp];
      if (NSEG == 3){
        fal[i] = *(const f16x8*)&sAl[cur][ap];
        fbl[i] = *(const f16x8*)&sBl[cur][bp];
      }
    }
    #pragma unroll
    for (int mi = 0; mi < 4; mi++)
      #pragma unroll
      for (int ni = 0; ni < 4; ni++)
        acc[mi][ni] = __builtin_amdgcn_mfma_f32_16x16x32_f16(fah[mi], fbh[ni], acc[mi][ni], 0,0,0);
    if (NSEG == 3){
      #pragma unroll
      for (int mi = 0; mi < 4; mi++)
        #pragma unroll
        for (int ni = 0; ni < 4; ni++)
          acc[mi][ni] = __builtin_amdgcn_mfma_f32_16x16x32_f16(fal[mi], fbh[ni], acc[mi][ni], 0,0,0);
      #pragma unroll
      for (int mi = 0; mi < 4; mi++)
        #pragma unroll
        for (int ni = 0; ni < 4; ni++)
          acc[mi][ni] = __builtin_amdgcn_mfma_f32_16x16x32_f16(fah[mi], fbl[ni], acc[mi][ni], 0,0,0);
    }
    __builtin_amdgcn_s_barrier();
  }

  #pragma unroll
  for (int ni = 0; ni < 4; ni++){
    const int gc = n0 + wc*64 + ni*16 + lr;
    float bias;
    if (MODE == MODE_UPMOD) bias = mask[(m0 >> 9) * H_DIM + gc] ? bias1[gc] : bias0[gc];
    else                    bias = bias0[gc];
    #pragma unroll
    for (int mi = 0; mi < 4; mi++){
      #pragma unroll
      for (int r = 0; r < 4; r++){
        const int gr = m0 + wr*64 + mi*16 + q*4 + r;
        const int cr = gr - c_row_base;
        float v = acc[mi][ni][r] + bias;
        if (MODE == MODE_G1){
          v = fmaxf(v, 0.f);
          size_t d = (img_g32(cr, gc >> 3, N >> 5) << 3) + (gc & 7);
          Chi[d] = (_Float16)v;
        }
        if (MODE == MODE_UPMOD){
          v = v / (1.f + __expf(-v));
          size_t d = (img_g32(cr, gc >> 3, N >> 5) << 3) + (gc & 7);
          Chi[d] = (_Float16)v;
        }
        if (MODE == MODE_DOWN) C32[(size_t)cr * N + gc] = v;
      }
    }
  }
}

// gate2 8-phase-class kernel (r22-proven): 256x256, triple-buffered,
// 4 phases/K-step, counted vmcnt(4) at phase 3 only, setprio around MFMA.
__global__ __launch_bounds__(512, 2)
void gemm_g2(const _Float16* __restrict__ A, const _Float16* __restrict__ B,
             const float* __restrict__ bias0,
             unsigned* __restrict__ keys, unsigned* __restrict__ Mkey,
             unsigned* __restrict__ hist, int N, int K, int batch_base)
{
  __shared__ __align__(16) _Float16 sAb[3][8192];
  __shared__ __align__(16) _Float16 sBb[3][8192];

  const int nbx = gridDim.x;
  const int h = blockIdx.y * nbx + blockIdx.x;
  const int xcd = h & 7, idx = h >> 3;
  const int cw = nbx >> 2, ch = gridDim.y >> 1;
  const int bx = (xcd & 3) * cw + idx % cw;
  const int by = (xcd >> 2) * ch + idx / cw;

  const int tid = threadIdx.x;
  const int lane = tid & 63;
  const int w = tid >> 6;
  const int wrow = w >> 2, wcol = w & 3;
  const int lr = lane & 15;
  const int q = lane >> 4;

  const int m0 = by * 256;
  const int n0 = bx * 256;
  const int nkt = K >> 5;
  const int ar0 = (m0 >> 7) * nkt;
  const int br0 = (n0 >> 7) * nkt;

  f32x4 acc[8][4];
  #pragma unroll
  for (int i = 0; i < 8; i++)
    #pragma unroll
    for (int j = 0; j < 4; j++) acc[i][j] = (f32x4){0.f,0.f,0.f,0.f};

  const int soff = (((((lr & 1) << 2) | q) ^ (lr >> 1)) << 3);
  int offA[8], offB[4];
  #pragma unroll
  for (int mi = 0; mi < 8; mi++) offA[mi] = ((mi*8 + (lr >> 1)) << 6) + soff;
  #pragma unroll
  for (int ni = 0; ni < 4; ni++)
    offB[ni] = (((wcol & 1)*32 + ni*8 + (lr >> 1)) << 6) + soff;
  const int arb = wrow * 4096;
  const int bcb = (wcol >> 1) * 4096;

  auto STA = [&](int buf, int rb, int kt){
    gload16(A + ((((size_t)(ar0 + rb*nkt + kt) << 9) + tid) << 3),
            &sAb[buf][rb*4096 + (tid << 3)]);
  };
  auto STB = [&](int buf, int cb, int kt){
    gload16(B + ((((size_t)(br0 + cb*nkt + kt) << 9) + tid) << 3),
            &sBb[buf][cb*4096 + (tid << 3)]);
  };

#define G2PHASE(P, STG)                                                        \
  {                                                                            \
    f16x8 a0 = *(const f16x8*)&sAb[cur][arb + offA[2*(P)]];                    \
    f16x8 a1 = *(const f16x8*)&sAb[cur][arb + offA[2*(P)+1]];                  \
    STG;                                                                       \
    if ((P) == 3){ if (pf) waitcnt_vm<4>(); else waitcnt_vm<0>(); }            \
    __builtin_amdgcn_s_barrier();                                              \
    asm volatile("s_waitcnt lgkmcnt(0)" ::: "memory");                         \
    __builtin_amdgcn_sched_barrier(0);                                         \
    __builtin_amdgcn_s_setprio(1);                                             \
    _Pragma("unroll")                                                          \
    for (int ni = 0; ni < 4; ni++)                                             \
      acc[2*(P)][ni]   = __builtin_amdgcn_mfma_f32_16x16x32_f16(a0, fb[ni], acc[2*(P)][ni], 0,0,0);   \
    _Pragma("unroll")                                                          \
    for (int ni = 0; ni < 4; ni++)                                             \
      acc[2*(P)+1][ni] = __builtin_amdgcn_mfma_f32_16x16x32_f16(a1, fb[ni], acc[2*(P)+1][ni], 0,0,0); \
    __builtin_amdgcn_s_setprio(0);                                             \
    __builtin_amdgcn_s_barrier();                                              \
  }

  STA(0,0,0); STB(0,0,0); STB(0,1,0); STA(0,1,0);
  STA(1,0,1); STB(1,0,1); STB(1,1,1); STA(1,1,1);
  waitcnt_vm<4>();
  __builtin_amdgcn_s_barrier();

  for (int kt = 0; kt < nkt; ++kt){
    const int cur = kt % 3, nb = (kt + 2) % 3;
    const bool pf = (kt + 2 < nkt);
    f16x8 fb[4];
    #pragma unroll
    for (int ni = 0; ni < 4; ni++)
      fb[ni] = *(const f16x8*)&sBb[cur][bcb + offB[ni]];
    G2PHASE(0, if (pf) STA(nb, 0, kt+2))
    G2PHASE(1, if (pf) STB(nb, 0, kt+2))
    G2PHASE(2, if (pf) STB(nb, 1, kt+2))
    G2PHASE(3, if (pf) STA(nb, 1, kt+2))
  }
#undef G2PHASE

  unsigned* lh = (unsigned*)&sAb[0][0];
  __syncthreads();
  for (int i = tid; i < 4096; i += 512) lh[i] = 0;
  __syncthreads();

  const int gb = batch_base + (m0 >> 9);
  #pragma unroll
  for (int ni = 0; ni < 4; ni++){
    const int gc = n0 + wcol*64 + ni*16 + lr;
    const float bias = bias0[gc];
    unsigned colmax = 0u;
    #pragma unroll
    for (int mi = 0; mi < 8; mi++){
      #pragma unroll
      for (int r = 0; r < 4; r++){
        const int gr = m0 + wrow*128 + mi*16 + q*4 + r;
        float v = acc[mi][ni][r] + bias;
        unsigned key = lkey(v);
        keys[(size_t)gr * N + gc] = key;
        colmax = max(colmax, key);
        atomicAdd(&lh[key >> 17], 1u);
      }
    }
    atomicMax(&Mkey[gb * H_DIM + gc], colmax);
  }
  __syncthreads();
  for (int i = tid; i < 4096; i += 512)
    if (lh[i]) atomicAdd(&hist[(gb << 12) + i], lh[i]);
}

// ---- exact k-th largest per batch: 12-bit hist (from gate2) + candidate refine ----

__global__ __launch_bounds__(256)
void select12(const unsigned* __restrict__ hist, unsigned* __restrict__ b12,
              unsigned* __restrict__ krem, unsigned* __restrict__ ccount, int b0)
{
  const int b = b0 + (int)blockIdx.x;
  __shared__ unsigned part[256];
  const unsigned base = (unsigned)b << 12;
  unsigned s = 0;
  #pragma unroll
  for (int i = 0; i < 16; i++) s += hist[base + threadIdx.x*16 + i];
  part[threadIdx.x] = s;
  __syncthreads();
  if (threadIdx.x == 0){
    unsigned cum = 0; int t = 255;
    for (; t > 0; --t){
      if (cum + part[t] >= K_SEL) break;
      cum += part[t];
    }
    int bin = 15; unsigned kr = K_SEL;
    for (; bin > 0; --bin){
      unsigned c = hist[base + t*16 + bin];
      if (cum + c >= K_SEL) break;
      cum += c;
    }
    kr = K_SEL - cum;
    b12[b] = (unsigned)(t*16 + bin);
    krem[b] = kr;
    ccount[b] = 0;
  }
}

// LDS-buffered match gather + ONE global atomic per WG (r8 fix)
__global__ __launch_bounds__(256)
void collect(const unsigned* __restrict__ keys, const unsigned* __restrict__ b12,
             unsigned* __restrict__ cand, unsigned* __restrict__ ccount, int b0)
{
  __shared__ unsigned cbuf[1024];
  __shared__ unsigned lcnt, gbase;
  const int bl = blockIdx.y;
  const int b  = b0 + bl;
  const unsigned bin = b12[b];
  if (threadIdx.x == 0) lcnt = 0;
  __syncthreads();
  const uint4* p = (const uint4*)(keys + (size_t)bl*2097152u + (size_t)blockIdx.x*8192u);
  uint4 kv[8];
  #pragma unroll
  for (int j = 0; j < 8; j++) kv[j] = p[threadIdx.x + j*256];
  #pragma unroll
  for (int j = 0; j < 8; j++){
    #pragma unroll
    for (int e = 0; e < 4; e++){
      unsigned k = (e==0)?kv[j].x:(e==1)?kv[j].y:(e==2)?kv[j].z:kv[j].w;
      if ((k >> 17) == bin){
        unsigned idx = atomicAdd(&lcnt, 1u);
        if (idx < 1024u) cbuf[idx] = k;
      }
    }
  }
  __syncthreads();
  const unsigned n = lcnt < 1024u ? lcnt : 1024u;
  if (threadIdx.x == 0) gbase = atomicAdd(&ccount[b], n);
  __syncthreads();
  const unsigned gb = gbase;
  for (unsigned i = threadIdx.x; i < n; i += 256){
    unsigned dst = gb + i;
    if (dst < CAND_CAP) cand[((size_t)b << 15) + dst] = cbuf[i];
  }
}

__global__ __launch_bounds__(256)
void select_exact(const unsigned* __restrict__ cand, const unsigned* __restrict__ ccount,
                  const unsigned* __restrict__ b12, const unsigned* __restrict__ kremA,
                  unsigned* __restrict__ tkey, int b0)
{
  const int b = b0 + (int)blockIdx.x;
  unsigned cc = ccount[b];
  const unsigned n = cc < CAND_CAP ? cc : CAND_CAP;
  __shared__ unsigned h[256];
  __shared__ unsigned sh2[2];
  unsigned prefix = b12[b] << 17;
  unsigned krem = kremA[b];
  const unsigned pm[3]  = {0xFFFE0000u, 0xFFFFFE00u, 0xFFFFFFFEu};
  const int      shs[3] = {9, 1, 0};
  const int      wid[3] = {256, 256, 2};
  for (int pass = 0; pass < 3; ++pass){
    if (threadIdx.x < (unsigned)wid[pass]) h[threadIdx.x] = 0;
    __syncthreads();
    for (unsigned i = threadIdx.x; i < n; i += 256){
      unsigned k = cand[((size_t)b << 15) + i];
      if ((k & pm[pass]) == prefix)
        atomicAdd(&h[(k >> shs[pass]) & (unsigned)(wid[pass]-1)], 1u);
    }
    __syncthreads();
    if (threadIdx.x == 0){
      unsigned cum = 0; int bin = wid[pass]-1;
      for (; bin > 0; --bin){
        unsigned c = h[bin];
        if (cum + c >= krem) break;
        cum += c;
      }
      krem -= cum;
      prefix |= ((unsigned)bin) << shs[pass];
      sh2[0] = prefix; sh2[1] = krem;
    }
    __syncthreads();
    prefix = sh2[0]; krem = sh2[1];
    __syncthreads();
  }
  if (threadIdx.x == 0) tkey[b] = prefix;
}

__global__ __launch_bounds__(256)
void make_mask(const unsigned* __restrict__ Mkey, const unsigned* __restrict__ tkey,
               unsigned* __restrict__ mask){
  const int i = blockIdx.x * 256 + threadIdx.x;   // B*H = 65536
  const int b = i >> 12;
  mask[i] = (Mkey[i] >= tkey[b]) ? 1u : 0u;
}

extern "C" void kernel_launch(void* const* d_in, const int* in_sizes, int n_in,
                              void* d_out, int out_size, void* d_ws, size_t ws_size,
                              hipStream_t stream)
{
  (void)in_sizes; (void)n_in; (void)out_size; (void)ws_size;
  const float* X      = (const float*)d_in[0];
  const float* up_w   = (const float*)d_in[1];
  const float* up_b   = (const float*)d_in[2];
  const float* g1w    = (const float*)d_in[3];
  const float* g1b    = (const float*)d_in[4];
  const float* g2w    = (const float*)d_in[5];
  const float* g2b    = (const float*)d_in[6];
  const float* mod_w  = (const float*)d_in[7];
  const float* mod_b  = (const float*)d_in[8];
  const float* down_w = (const float*)d_in[9];
  const float* down_b = (const float*)d_in[10];
  float* out = (float*)d_out;

  // ws layout (peak ~235 MiB)
  char* ws = (char*)d_ws;
  _Float16* Xhi  = (_Float16*)(ws);
  _Float16* Xlo  = (_Float16*)(ws + (16ull<<20));
  _Float16* G1hi = (_Float16*)(ws + (32ull<<20));
  _Float16* G1lo = (_Float16*)(ws + (40ull<<20));
  _Float16* G2hi = (_Float16*)(ws + (48ull<<20));
  _Float16* UPhi = (_Float16*)(ws + (112ull<<20));
  _Float16* MODhi= (_Float16*)(ws + (120ull<<20));
  _Float16* DWhi = (_Float16*)(ws + (128ull<<20));
  _Float16* Fhi  = (_Float16*)(ws + (136ull<<20));   // per half [4096][4096] (32 MiB)
  unsigned* keys = (unsigned*)(ws + (168ull<<20));   // per half [4096][4096] u32 (64 MiB)
  _Float16* Hbuf = (_Float16*)(ws + (136ull<<20));   // reuse F+keys after selection
  char* aux = ws + (232ull<<20);
  unsigned* Mkey  = (unsigned*)(aux);                 // 256 KB
  unsigned* maskb = (unsigned*)(aux + 262144);        // 256 KB
  unsigned* hist  = (unsigned*)(aux + 524288);        // 256 KB (16 batches x 4096)
  unsigned* cand  = (unsigned*)(aux + 786432);        // 2 MiB (16 x 32768)
  unsigned* b12   = (unsigned*)(aux + 786432 + 2097152);
  unsigned* krem  = (unsigned*)(aux + 786432 + 2097152 + 64);
  unsigned* ccnt  = (unsigned*)(aux + 786432 + 2097152 + 128);
  unsigned* tkey  = (unsigned*)(aux + 786432 + 2097152 + 192);

  // fused pack (3-seg gate1: G1lo packed; G2lo not)
  pack_all<<<20480, 256, 0, stream>>>(X, g1w, g2w, up_w, mod_w, down_w,
                                      Xhi, Xlo, G1hi, G1lo, G2hi, nullptr,
                                      UPhi, MODhi, DWhi);

  hipMemsetAsync(Mkey, 0, 262144, stream);
  hipMemsetAsync(hist, 0, 262144, stream);

  for (int half = 0; half < 2; ++half){
    const int b0 = half * 8;
    // gate1 half (3-seg, 2-phase): F(hi) = relu(X @ g1w^T + g1b)  [4096x4096], K=1024
    gemm_t<MODE_G1><<<dim3(32, 32), 256, 0, stream>>>(
        Xhi, Xlo, G1hi, G1lo, g1b, nullptr, nullptr,
        Fhi, nullptr, nullptr, H_DIM, D_DIM, half*4096, half*4096);
    // gate2 half (1-seg fp16, 8-phase-class 256^2): keys + Mkey + hist
    gemm_g2<<<dim3(16, 16), 512, 0, stream>>>(
        Fhi, G2hi, g2b, keys, Mkey, hist, H_DIM, H_DIM, b0);
    select12<<<8, 256, 0, stream>>>(hist, b12, krem, ccnt, b0);
    collect<<<dim3(256, 8), 256, 0, stream>>>(keys, b12, cand, ccnt, b0);
    select_exact<<<8, 256, 0, stream>>>(cand, ccnt, b12, krem, tkey, b0);
  }
  make_mask<<<256, 256, 0, stream>>>(Mkey, tkey, maskb);

  // up/mod (per-granule stage select, 3-deep) + silu -> Hbuf  [8192 x 4096], K=1024
  gemm_t<MODE_UPMOD><<<dim3(32, 64), 256, 0, stream>>>(
      Xhi, nullptr, UPhi, MODhi, up_b, mod_b, maskb,
      Hbuf, nullptr, nullptr, H_DIM, D_DIM, 0, 0);
  // down (3-deep): out = Hbuf @ down_w^T + down_b  [8192 x 1024], K=4096
  gemm_t<MODE_DOWN><<<dim3(8, 64), 256, 0, stream>>>(
      Hbuf, nullptr, DWhi, nullptr, down_b, nullptr, nullptr,
      nullptr, nullptr, out, D_DIM, H_DIM, 0, 0);
}